// Round 4
// baseline (252.657 us; speedup 1.0000x reference)
//
#include <hip/hip_runtime.h>
#include <hip/hip_bf16.h>

typedef unsigned short u16;
typedef unsigned int   u32;
typedef __attribute__((ext_vector_type(8)))  short bf16x8;
typedef __attribute__((ext_vector_type(16))) float f32x16;

#define N_S   8192
#define M_TOT 10240
#define SEGS  8
#define SEG   1024
#define QT    320     // 32-row q-tiles over M_TOT

__device__ __forceinline__ u16 f2bf(float f) {
  u32 x = __float_as_uint(f);
  u32 r = x + 0x7FFFu + ((x >> 16) & 1u);
  return (u16)(r >> 16);
}
__device__ __forceinline__ float bf2f(u16 h) {
  return __uint_as_float(((u32)h) << 16);
}

// ---------------------------------------------------------------- x = A @ W^T + b  (bf16 MFMA, fp32 accum)
__global__ __launch_bounds__(256) void gemm_x(const float* __restrict__ data,
                                              const float* __restrict__ inp,
                                              const float* __restrict__ W,
                                              const float* __restrict__ bias,
                                              float* __restrict__ x)
{
  __shared__ __align__(16) u16 At[64 * 256];   // 32KB, XOR-swizzled
  __shared__ __align__(16) u16 Wt[64 * 256];   // 32KB, XOR-swizzled
  const int t  = threadIdx.x;
  const int rb = blockIdx.x * 64, cb = blockIdx.y * 64;

#pragma unroll
  for (int it = 0; it < 8; ++it) {
    int c = it * 256 + t;                    // chunk of 8 bf16
    int row = c >> 5, c8 = c & 31;
    int grow = rb + row;
    const float* src = (grow < N_S) ? data + (size_t)grow * 256 + c8 * 8
                                    : inp + (size_t)(grow - N_S) * 256 + c8 * 8;
    float4 v0 = *(const float4*)src;
    float4 v1 = *(const float4*)(src + 4);
    u16 h[8] = {f2bf(v0.x), f2bf(v0.y), f2bf(v0.z), f2bf(v0.w),
                f2bf(v1.x), f2bf(v1.y), f2bf(v1.z), f2bf(v1.w)};
    *(int4*)((char*)At + row * 512 + ((c8 * 16) ^ ((row & 7) << 4))) = *(int4*)h;

    const float* wsrc = W + (size_t)(cb + row) * 256 + c8 * 8;
    float4 w0 = *(const float4*)wsrc;
    float4 w1 = *(const float4*)(wsrc + 4);
    u16 g[8] = {f2bf(w0.x), f2bf(w0.y), f2bf(w0.z), f2bf(w0.w),
                f2bf(w1.x), f2bf(w1.y), f2bf(w1.z), f2bf(w1.w)};
    *(int4*)((char*)Wt + row * 512 + ((c8 * 16) ^ ((row & 7) << 4))) = *(int4*)g;
  }
  __syncthreads();

  const int w = t >> 6, lane = t & 63, l31 = lane & 31, hi = lane >> 5;
  const int wr = (w >> 1) * 32, wc = (w & 1) * 32;
  f32x16 acc;
#pragma unroll
  for (int r = 0; r < 16; ++r) acc[r] = 0.f;
  const char* Ab = (const char*)At + (size_t)(wr + l31) * 512;
  const char* Bb = (const char*)Wt + (size_t)(wc + l31) * 512;
  const int rx = (l31 & 7) << 4;
#pragma unroll
  for (int k0 = 0; k0 < 256; k0 += 16) {
    bf16x8 af = *(const bf16x8*)(Ab + ((k0 * 2 + hi * 16) ^ rx));
    bf16x8 bfv = *(const bf16x8*)(Bb + ((k0 * 2 + hi * 16) ^ rx));
    acc = __builtin_amdgcn_mfma_f32_32x32x16_bf16(af, bfv, acc, 0, 0, 0);
  }
  float bv = bias[cb + wc + l31];
#pragma unroll
  for (int r = 0; r < 16; ++r) {
    int qr = (r & 3) + 8 * (r >> 2) + 4 * hi;
    x[(size_t)(rb + wr + qr) * 256 + cb + wc + l31] = acc[r] + bv;
  }
}

// ---------------------------------------------------------------- csbT[i][c][r] = bf16(c_ss[r][i*64+c])
__global__ __launch_bounds__(256) void prep_csT(const float* __restrict__ css,
                                                u16* __restrict__ csbT)
{
  __shared__ float tile[64][65];
  const int i  = blockIdx.y;
  const int r0 = blockIdx.x * 64;
  const int t  = threadIdx.x;
#pragma unroll
  for (int it = 0; it < 4; ++it) {
    int r  = (t >> 4) + it * 16;
    int c4 = (t & 15) * 4;
    float4 v = *(const float4*)(css + (size_t)(r0 + r) * 192 + i * 64 + c4);
    tile[r][c4] = v.x; tile[r][c4 + 1] = v.y; tile[r][c4 + 2] = v.z; tile[r][c4 + 3] = v.w;
  }
  __syncthreads();
  const int c = t >> 2, rq = (t & 3) * 16;
  u16 tmp[16];
#pragma unroll
  for (int e = 0; e < 16; ++e) tmp[e] = f2bf(tile[rq + e][c]);
  u16* dst = csbT + (size_t)i * (64 * (size_t)N_S) + (size_t)c * N_S + r0 + rq;
  *(int4*)dst       = *(int4*)tmp;
  *(int4*)(dst + 8) = *(int4*)(tmp + 8);
}

// ---------------------------------------------------------------- reg_w = sum(W^2)+sum(b^2)
__global__ __launch_bounds__(256) void regw_ker(const float* __restrict__ W,
                                                const float* __restrict__ bias,
                                                float* __restrict__ outslot)
{
  __shared__ float red[256];
  float s = 0.f;
  for (int idx = threadIdx.x; idx < 65536; idx += 256) { float w = W[idx]; s += w * w; }
  { float bv = bias[threadIdx.x]; s += bv * bv; }
  red[threadIdx.x] = s; __syncthreads();
#pragma unroll
  for (int o = 128; o; o >>= 1) {
    if (threadIdx.x < o) red[threadIdx.x] += red[threadIdx.x + o];
    __syncthreads();
  }
  if (threadIdx.x == 0) *outslot = red[0];
}

// ---------------------------------------------------------------- bf16 chunk + Dekker-split 0.5*|row|^2 (from bf16 values)
__global__ __launch_bounds__(256) void prep_xb(const float* __restrict__ x, int j,
                                               u16* __restrict__ xbj, u32* __restrict__ hlj)
{
  const int w = threadIdx.x >> 6, lane = threadIdx.x & 63;
  const int row = blockIdx.x * 4 + w;
  float v = x[(size_t)row * 256 + (size_t)j * 64 + lane];
  u16 h = f2bf(v);
  float f = bf2f(h);
  xbj[(size_t)row * 64 + lane] = h;
  float s = f * f;
#pragma unroll
  for (int o = 32; o; o >>= 1) s += __shfl_xor(s, o);
  if (lane == 0) {
    float A  = 0.5f * s;
    u16  hq  = f2bf(A);
    u16  lq  = f2bf(A - bf2f(hq));
    hlj[row] = (u32)hq | ((u32)lq << 16);
  }
}

// ---------------------------------------------------------------- screen: activity bits for one j, massively parallel
// grid (QT, SEGS), 4 waves/block; wave w covers k-tiles [seg*32 + w*8, +8)
__global__ __launch_bounds__(256) void screen_ker(const u16* __restrict__ xbj,
                                                  const u32* __restrict__ hlj,
                                                  u32* __restrict__ maskj)
{
  const int t = threadIdx.x;
  const int w = t >> 6, lane = t & 63, l31 = lane & 31, hi = lane >> 5;
  const int qtile = blockIdx.x;
  const int seg   = blockIdx.y;
  const int qrow  = qtile * 32 + l31;

  const u16* qp = xbj + (size_t)qrow * 64 + hi * 8;
  bf16x8 qf0 = *(const bf16x8*)(qp);
  bf16x8 qf1 = *(const bf16x8*)(qp + 16);
  bf16x8 qf2 = *(const bf16x8*)(qp + 32);
  bf16x8 qf3 = *(const bf16x8*)(qp + 48);
  u32 hlq = hlj[qrow];
  union { bf16x8 v; u32 d[4]; } qe, ke;
  qe.d[0] = hi ? 0u : hlq;
  qe.d[1] = hi ? 0u : 0x3F803F80u;
  qe.d[2] = 0u; qe.d[3] = 0u;
  ke.d[2] = 0u; ke.d[3] = 0u;
  const u32 ke0 = hi ? 0u : 0xBF80BF80u;

  f32x16 Z;
#pragma unroll
  for (int r = 0; r < 16; ++r) Z[r] = 0.f;

  u32 bits = 0;
  const int nt0 = seg * 32 + w * 8;
#pragma unroll
  for (int it = 0; it < 8; ++it) {
    const int nb = (nt0 + it) * 32;
    const u16* kp = xbj + (size_t)(nb + l31) * 64 + hi * 8;
    bf16x8 kf0 = *(const bf16x8*)(kp);
    bf16x8 kf1 = *(const bf16x8*)(kp + 16);
    bf16x8 kf2 = *(const bf16x8*)(kp + 32);
    bf16x8 kf3 = *(const bf16x8*)(kp + 48);
    u32 hlk = hlj[nb + l31];
    ke.d[0] = ke0;
    ke.d[1] = hi ? 0u : (hlk ^ 0x80008000u);
    f32x16 S = __builtin_amdgcn_mfma_f32_32x32x16_bf16(qf0, kf0, Z, 0, 0, 0);
    S = __builtin_amdgcn_mfma_f32_32x32x16_bf16(qf1, kf1, S, 0, 0, 0);
    S = __builtin_amdgcn_mfma_f32_32x32x16_bf16(qf2, kf2, S, 0, 0, 0);
    S = __builtin_amdgcn_mfma_f32_32x32x16_bf16(qf3, kf3, S, 0, 0, 0);
    S = __builtin_amdgcn_mfma_f32_32x32x16_bf16(qe.v, ke.v, S, 0, 0, 0);
    float m0 = fmaxf(S[0], S[1]),  m1 = fmaxf(S[2], S[3]);
    float m2 = fmaxf(S[4], S[5]),  m3 = fmaxf(S[6], S[7]);
    float m4 = fmaxf(S[8], S[9]),  m5 = fmaxf(S[10], S[11]);
    float m6 = fmaxf(S[12], S[13]), m7 = fmaxf(S[14], S[15]);
    float mx = fmaxf(fmaxf(fmaxf(m0, m1), fmaxf(m2, m3)),
                     fmaxf(fmaxf(m4, m5), fmaxf(m6, m7)));
    bits |= (__any(mx > -25.0f) ? 1u : 0u) << it;
  }
  if (lane == 0)
    ((unsigned char*)maskj)[((size_t)qtile * SEGS + seg) * 4 + w] = (unsigned char)bits;
}

// ---------------------------------------------------------------- fused: val_seg = (sum_j K_j) @ cs_i, active tiles only
template<int NJ>
__global__ __launch_bounds__(256) void fused_ker(const u16* __restrict__ xb,
                                                 const u32* __restrict__ hl,
                                                 const u16* __restrict__ csbT,
                                                 float* __restrict__ val,
                                                 const u32* __restrict__ mask)
{
  __shared__ __align__(16) u16 Pt[4][32 * 32];   // per-wave P transpose buffer

  const int t    = threadIdx.x;
  const int w    = t >> 6;
  const int lane = t & 63;
  const int l31  = lane & 31;
  const int hi   = lane >> 5;
  const int seg   = blockIdx.y;
  const int qtile = blockIdx.x * 4 + w;
  const int qrow  = qtile * 32 + l31;

  u32 m[NJ];
  u32 uni = 0;
#pragma unroll
  for (int j = 0; j < NJ; ++j) {
    m[j] = mask[((size_t)j * QT + qtile) * SEGS + seg];
    uni |= m[j];
  }
  if (!uni) return;

  float* vout = val + (size_t)seg * ((size_t)M_TOT * 64);

  bf16x8 qf[NJ][4];
  u32    hlq[NJ];
#pragma unroll
  for (int j = 0; j < NJ; ++j) {
    const u16* xbj = xb + (size_t)j * ((size_t)M_TOT * 64);
#pragma unroll
    for (int dk = 0; dk < 4; ++dk)
      qf[j][dk] = *(const bf16x8*)(xbj + (size_t)qrow * 64 + dk * 16 + hi * 8);
    hlq[j] = hl[j * M_TOT + qrow];
  }

  f32x16 acc0, acc1;
#pragma unroll
  for (int r = 0; r < 16; ++r) { acc0[r] = 0.f; acc1[r] = 0.f; }
  const int nb0 = seg * SEG;

  u32 rem = uni;
  while (rem) {
    const int nt = __ffs(rem) - 1;
    rem &= rem - 1;
    const int nb = nb0 + nt * 32;
    f32x16 P;
#pragma unroll
    for (int r = 0; r < 16; ++r) P[r] = 0.f;
#pragma unroll
    for (int j = 0; j < NJ; ++j) {
      if ((m[j] >> nt) & 1u) {
        const u16* xbj = xb + (size_t)j * ((size_t)M_TOT * 64);
        const u16* kp = xbj + (size_t)(nb + l31) * 64 + hi * 8;
        bf16x8 kf0 = *(const bf16x8*)(kp);
        bf16x8 kf1 = *(const bf16x8*)(kp + 16);
        bf16x8 kf2 = *(const bf16x8*)(kp + 32);
        bf16x8 kf3 = *(const bf16x8*)(kp + 48);
        u32 hlk = hl[j * M_TOT + nb + l31];
        f32x16 S;
#pragma unroll
        for (int r = 0; r < 16; ++r) S[r] = 0.f;
        S = __builtin_amdgcn_mfma_f32_32x32x16_bf16(qf[j][0], kf0, S, 0, 0, 0);
        S = __builtin_amdgcn_mfma_f32_32x32x16_bf16(qf[j][1], kf1, S, 0, 0, 0);
        S = __builtin_amdgcn_mfma_f32_32x32x16_bf16(qf[j][2], kf2, S, 0, 0, 0);
        S = __builtin_amdgcn_mfma_f32_32x32x16_bf16(qf[j][3], kf3, S, 0, 0, 0);
        union { bf16x8 v; u32 d[4]; } qe, ke;
        qe.d[0] = hi ? 0u : hlq[j];
        qe.d[1] = hi ? 0u : 0x3F803F80u;
        qe.d[2] = 0u; qe.d[3] = 0u;
        ke.d[0] = hi ? 0u : 0xBF80BF80u;
        ke.d[1] = hi ? 0u : (hlk ^ 0x80008000u);
        ke.d[2] = 0u; ke.d[3] = 0u;
        S = __builtin_amdgcn_mfma_f32_32x32x16_bf16(qe.v, ke.v, S, 0, 0, 0);
#pragma unroll
        for (int r = 0; r < 16; ++r) P[r] += __expf(S[r]);
      }
    }
    // P (D-layout) -> LDS (bf16) -> A-layout, per-wave region
    char* pw = (char*)&Pt[w][0];
#pragma unroll
    for (int r = 0; r < 16; ++r) {
      int qr = (r & 3) + 8 * (r >> 2) + 4 * hi;
      *(u16*)(pw + qr * 64 + ((l31 * 2) ^ ((qr & 3) << 4))) = f2bf(P[r]);
    }
    asm volatile("s_waitcnt lgkmcnt(0)" ::: "memory");
    bf16x8 pa0 = *(const bf16x8*)(pw + l31 * 64 + ((0  + hi * 16) ^ ((l31 & 3) << 4)));
    bf16x8 pa1 = *(const bf16x8*)(pw + l31 * 64 + ((32 + hi * 16) ^ ((l31 & 3) << 4)));
    asm volatile("s_waitcnt lgkmcnt(0)" ::: "memory");   // drain before next nt's writes (WAR)
    bf16x8 v00 = *(const bf16x8*)(csbT + (size_t)l31 * N_S + nb + hi * 8);
    bf16x8 v01 = *(const bf16x8*)(csbT + (size_t)l31 * N_S + nb + 16 + hi * 8);
    bf16x8 v10 = *(const bf16x8*)(csbT + (size_t)(32 + l31) * N_S + nb + hi * 8);
    bf16x8 v11 = *(const bf16x8*)(csbT + (size_t)(32 + l31) * N_S + nb + 16 + hi * 8);
    acc0 = __builtin_amdgcn_mfma_f32_32x32x16_bf16(pa0, v00, acc0, 0, 0, 0);
    acc0 = __builtin_amdgcn_mfma_f32_32x32x16_bf16(pa1, v01, acc0, 0, 0, 0);
    acc1 = __builtin_amdgcn_mfma_f32_32x32x16_bf16(pa0, v10, acc1, 0, 0, 0);
    acc1 = __builtin_amdgcn_mfma_f32_32x32x16_bf16(pa1, v11, acc1, 0, 0, 0);
  }

#pragma unroll
  for (int r = 0; r < 16; ++r) {
    int qr = (r & 3) + 8 * (r >> 2) + 4 * hi;
    size_t row = (size_t)(qtile * 32 + qr);
    vout[row * 64 + l31]      = acc0[r];
    vout[row * 64 + 32 + l31] = acc1[r];
  }
}

// ---------------------------------------------------------------- apply: x[:,i+1] += val (active segs from masks); dot partials
__global__ __launch_bounds__(256) void apply_ker(const float* __restrict__ val,
                                                 const float* __restrict__ css,
                                                 float* __restrict__ x, int i, int nj,
                                                 const u32* __restrict__ mask,
                                                 float* __restrict__ dotpart)
{
  __shared__ float red[256];
  const int t = threadIdx.x;
  const int qtile = blockIdx.x;
  const int row = qtile * 32 + (t >> 3);
  const int coff = (t & 7) * 8;
  bool f[SEGS];
  bool anyf = false;
#pragma unroll
  for (int s = 0; s < SEGS; ++s) {
    u32 u = 0;
    for (int j = 0; j < nj; ++j) u |= mask[((size_t)j * QT + qtile) * SEGS + s];
    f[s] = (u != 0);
    anyf = anyf || f[s];
  }
  float dp = 0.f;
  if (anyf) {
    float v[8];
#pragma unroll
    for (int e = 0; e < 8; ++e) v[e] = 0.f;
#pragma unroll
    for (int s = 0; s < SEGS; ++s) if (f[s]) {
      const float* vp = val + (size_t)s * ((size_t)M_TOT * 64) + (size_t)row * 64 + coff;
      float4 a = *(const float4*)vp;
      float4 b = *(const float4*)(vp + 4);
      v[0] += a.x; v[1] += a.y; v[2] += a.z; v[3] += a.w;
      v[4] += b.x; v[5] += b.y; v[6] += b.z; v[7] += b.w;
    }
    float* xp = x + (size_t)row * 256 + (size_t)(i + 1) * 64 + coff;
    float4 xa = *(const float4*)xp;
    float4 xb4 = *(const float4*)(xp + 4);
    xa.x += v[0]; xa.y += v[1]; xa.z += v[2]; xa.w += v[3];
    xb4.x += v[4]; xb4.y += v[5]; xb4.z += v[6]; xb4.w += v[7];
    *(float4*)xp = xa;
    *(float4*)(xp + 4) = xb4;
    if (row < N_S) {
      const float* cp = css + (size_t)row * 192 + (size_t)i * 64 + coff;
      float4 ca = *(const float4*)cp;
      float4 cb = *(const float4*)(cp + 4);
      dp = ca.x * v[0] + ca.y * v[1] + ca.z * v[2] + ca.w * v[3]
         + cb.x * v[4] + cb.y * v[5] + cb.z * v[6] + cb.w * v[7];
    }
  }
  red[t] = dp; __syncthreads();
#pragma unroll
  for (int o = 128; o; o >>= 1) {
    if (t < o) red[t] += red[t + o];
    __syncthreads();
  }
  if (t == 0) dotpart[i * QT + qtile] = red[0];
}

// ---------------------------------------------------------------- reg final reduce (fixed order)
__global__ __launch_bounds__(256) void regfinal_ker(const float* __restrict__ regw,
                                                    const float* __restrict__ dotpart,
                                                    float* __restrict__ out)
{
  __shared__ float red[256];
  float s = 0.f;
  for (int idx = threadIdx.x; idx < 3 * QT; idx += 256) s += dotpart[idx];
  red[threadIdx.x] = s; __syncthreads();
#pragma unroll
  for (int o = 128; o; o >>= 1) {
    if (threadIdx.x < o) red[threadIdx.x] += red[threadIdx.x + o];
    __syncthreads();
  }
  if (threadIdx.x == 0) out[0] = red[0] + regw[0];
}

// ---------------------------------------------------------------- output copy
__global__ __launch_bounds__(256) void outcopy_ker(const float* __restrict__ x,
                                                   float* __restrict__ out)
{
  int idx = blockIdx.x * 256 + threadIdx.x;   // < 131072
  int r = idx >> 6, c = idx & 63;
  out[idx] = x[(size_t)(N_S + r) * 256 + 192 + c];
}

// ================================================================ launch
extern "C" void kernel_launch(void* const* d_in, const int* in_sizes, int n_in,
                              void* d_out, int out_size, void* d_ws, size_t ws_size,
                              hipStream_t stream)
{
  const float* data = (const float*)d_in[0];
  const float* inp  = (const float*)d_in[1];
  const float* W    = (const float*)d_in[2];
  const float* bias = (const float*)d_in[3];
  const float* css  = (const float*)d_in[4];
  float* out = (float*)d_out;

  char* ws = (char*)d_ws;
  const size_t OFF_X    = 0;                         // 10,485,760
  const size_t OFF_XB   = 10485760;                  //  3,932,160
  const size_t OFF_HL   = OFF_XB + 3932160;          //    122,880
  const size_t OFF_CSBT = OFF_HL + 122880;           //  3,145,728
  const size_t OFF_VAL  = OFF_CSBT + 3145728;        // 20,971,520
  const size_t OFF_MASK = OFF_VAL + 20971520;        //     30,720
  const size_t OFF_REGW = OFF_MASK + 30720;          //        256
  const size_t OFF_DOT  = OFF_REGW + 256;            //      3,840

  float* x      = (float*)(ws + OFF_X);
  u16*   xb     = (u16*)  (ws + OFF_XB);
  u32*   hl     = (u32*)  (ws + OFF_HL);
  u16*   csbT   = (u16*)  (ws + OFF_CSBT);
  float* val    = (float*)(ws + OFF_VAL);
  u32*   mask   = (u32*)  (ws + OFF_MASK);
  float* regw   = (float*)(ws + OFF_REGW);
  float* dotpart= (float*)(ws + OFF_DOT);

  const size_t XB_STRIDE = (size_t)M_TOT * 64;     // u16 elems
  const size_t CS_STRIDE = (size_t)64 * N_S;       // u16 elems
  const size_t MK_STRIDE = (size_t)QT * SEGS;      // u32 elems

  gemm_x   <<<dim3(160, 4), 256, 0, stream>>>(data, inp, W, bias, x);
  prep_csT <<<dim3(128, 3), 256, 0, stream>>>(css, csbT);
  regw_ker <<<1, 256, 0, stream>>>(W, bias, regw);
  prep_xb  <<<2560, 256, 0, stream>>>(x, 0, xb, hl);
  screen_ker<<<dim3(QT, SEGS), 256, 0, stream>>>(xb, hl, mask);

  // i = 0
  fused_ker<1><<<dim3(80, SEGS), 256, 0, stream>>>(xb, hl, csbT, val, mask);
  apply_ker<<<QT, 256, 0, stream>>>(val, css, x, 0, 1, mask, dotpart);
  prep_xb  <<<2560, 256, 0, stream>>>(x, 1, xb + XB_STRIDE, hl + M_TOT);
  screen_ker<<<dim3(QT, SEGS), 256, 0, stream>>>(xb + XB_STRIDE, hl + M_TOT, mask + MK_STRIDE);

  // i = 1
  fused_ker<2><<<dim3(80, SEGS), 256, 0, stream>>>(xb, hl, csbT + CS_STRIDE, val, mask);
  apply_ker<<<QT, 256, 0, stream>>>(val, css, x, 1, 2, mask, dotpart);
  prep_xb  <<<2560, 256, 0, stream>>>(x, 2, xb + 2 * XB_STRIDE, hl + 2 * M_TOT);
  screen_ker<<<dim3(QT, SEGS), 256, 0, stream>>>(xb + 2 * XB_STRIDE, hl + 2 * M_TOT, mask + 2 * MK_STRIDE);

  // i = 2
  fused_ker<3><<<dim3(80, SEGS), 256, 0, stream>>>(xb, hl, csbT + 2 * CS_STRIDE, val, mask);
  apply_ker<<<QT, 256, 0, stream>>>(val, css, x, 2, 3, mask, dotpart);

  regfinal_ker<<<1, 256, 0, stream>>>(regw, dotpart, out + 131072);
  outcopy_ker <<<512, 256, 0, stream>>>(x, out);
}

// Round 5
// 215.575 us; speedup vs baseline: 1.1720x; 1.1720x over previous
//
#include <hip/hip_runtime.h>
#include <hip/hip_bf16.h>

typedef unsigned short u16;
typedef unsigned int   u32;
typedef __attribute__((ext_vector_type(8)))  short bf16x8;
typedef __attribute__((ext_vector_type(16))) float f32x16;

#define N_S   8192
#define M_TOT 10240
#define SEGS  8
#define SEG   1024
#define QT    320     // 32-row q-tiles over M_TOT

__device__ __forceinline__ u16 f2bf(float f) {
  u32 x = __float_as_uint(f);
  u32 r = x + 0x7FFFu + ((x >> 16) & 1u);
  return (u16)(r >> 16);
}
__device__ __forceinline__ float bf2f(u16 h) {
  return __uint_as_float(((u32)h) << 16);
}

// ---------------------------------------------------------------- x = A @ W^T + b  (bf16 MFMA, fp32 accum)
__global__ __launch_bounds__(256) void gemm_x(const float* __restrict__ data,
                                              const float* __restrict__ inp,
                                              const float* __restrict__ W,
                                              const float* __restrict__ bias,
                                              float* __restrict__ x)
{
  __shared__ __align__(16) u16 At[64 * 256];   // 32KB, XOR-swizzled
  __shared__ __align__(16) u16 Wt[64 * 256];   // 32KB, XOR-swizzled
  const int t  = threadIdx.x;
  const int rb = blockIdx.x * 64, cb = blockIdx.y * 64;

#pragma unroll
  for (int it = 0; it < 8; ++it) {
    int c = it * 256 + t;                    // chunk of 8 bf16
    int row = c >> 5, c8 = c & 31;
    int grow = rb + row;
    const float* src = (grow < N_S) ? data + (size_t)grow * 256 + c8 * 8
                                    : inp + (size_t)(grow - N_S) * 256 + c8 * 8;
    float4 v0 = *(const float4*)src;
    float4 v1 = *(const float4*)(src + 4);
    u16 h[8] = {f2bf(v0.x), f2bf(v0.y), f2bf(v0.z), f2bf(v0.w),
                f2bf(v1.x), f2bf(v1.y), f2bf(v1.z), f2bf(v1.w)};
    *(int4*)((char*)At + row * 512 + ((c8 * 16) ^ ((row & 7) << 4))) = *(int4*)h;

    const float* wsrc = W + (size_t)(cb + row) * 256 + c8 * 8;
    float4 w0 = *(const float4*)wsrc;
    float4 w1 = *(const float4*)(wsrc + 4);
    u16 g[8] = {f2bf(w0.x), f2bf(w0.y), f2bf(w0.z), f2bf(w0.w),
                f2bf(w1.x), f2bf(w1.y), f2bf(w1.z), f2bf(w1.w)};
    *(int4*)((char*)Wt + row * 512 + ((c8 * 16) ^ ((row & 7) << 4))) = *(int4*)g;
  }
  __syncthreads();

  const int w = t >> 6, lane = t & 63, l31 = lane & 31, hi = lane >> 5;
  const int wr = (w >> 1) * 32, wc = (w & 1) * 32;
  f32x16 acc;
#pragma unroll
  for (int r = 0; r < 16; ++r) acc[r] = 0.f;
  const char* Ab = (const char*)At + (size_t)(wr + l31) * 512;
  const char* Bb = (const char*)Wt + (size_t)(wc + l31) * 512;
  const int rx = (l31 & 7) << 4;
#pragma unroll
  for (int k0 = 0; k0 < 256; k0 += 16) {
    bf16x8 af = *(const bf16x8*)(Ab + ((k0 * 2 + hi * 16) ^ rx));
    bf16x8 bfv = *(const bf16x8*)(Bb + ((k0 * 2 + hi * 16) ^ rx));
    acc = __builtin_amdgcn_mfma_f32_32x32x16_bf16(af, bfv, acc, 0, 0, 0);
  }
  float bv = bias[cb + wc + l31];
#pragma unroll
  for (int r = 0; r < 16; ++r) {
    int qr = (r & 3) + 8 * (r >> 2) + 4 * hi;
    x[(size_t)(rb + wr + qr) * 256 + cb + wc + l31] = acc[r] + bv;
  }
}

// ---------------------------------------------------------------- csbT[i][c][r] = bf16(c_ss[r][i*64+c])
__global__ __launch_bounds__(256) void prep_csT(const float* __restrict__ css,
                                                u16* __restrict__ csbT)
{
  __shared__ float tile[64][65];
  const int i  = blockIdx.y;
  const int r0 = blockIdx.x * 64;
  const int t  = threadIdx.x;
#pragma unroll
  for (int it = 0; it < 4; ++it) {
    int r  = (t >> 4) + it * 16;
    int c4 = (t & 15) * 4;
    float4 v = *(const float4*)(css + (size_t)(r0 + r) * 192 + i * 64 + c4);
    tile[r][c4] = v.x; tile[r][c4 + 1] = v.y; tile[r][c4 + 2] = v.z; tile[r][c4 + 3] = v.w;
  }
  __syncthreads();
  const int c = t >> 2, rq = (t & 3) * 16;
  u16 tmp[16];
#pragma unroll
  for (int e = 0; e < 16; ++e) tmp[e] = f2bf(tile[rq + e][c]);
  u16* dst = csbT + (size_t)i * (64 * (size_t)N_S) + (size_t)c * N_S + r0 + rq;
  *(int4*)dst       = *(int4*)tmp;
  *(int4*)(dst + 8) = *(int4*)(tmp + 8);
}

// ---------------------------------------------------------------- reg_w partials: 64 blocks, fixed-order
__global__ __launch_bounds__(256) void regw_ker(const float* __restrict__ W,
                                                const float* __restrict__ bias,
                                                float* __restrict__ regpart)
{
  __shared__ float red[256];
  const int t = threadIdx.x, b = blockIdx.x;
  float4 v = *(const float4*)(W + (size_t)b * 1024 + t * 4);
  float s = v.x * v.x + v.y * v.y + v.z * v.z + v.w * v.w;
  if (b == 0) { float bv = bias[t]; s += bv * bv; }
  red[t] = s; __syncthreads();
#pragma unroll
  for (int o = 128; o; o >>= 1) {
    if (t < o) red[t] += red[t + o];
    __syncthreads();
  }
  if (t == 0) regpart[b] = red[0];
}

// ---------------------------------------------------------------- bf16 chunk + Dekker-split 0.5*|row|^2 (from bf16 values)
__global__ __launch_bounds__(256) void prep_xb(const float* __restrict__ x, int j,
                                               u16* __restrict__ xbj, u32* __restrict__ hlj)
{
  const int w = threadIdx.x >> 6, lane = threadIdx.x & 63;
  const int row = blockIdx.x * 4 + w;
  float v = x[(size_t)row * 256 + (size_t)j * 64 + lane];
  u16 h = f2bf(v);
  float f = bf2f(h);
  xbj[(size_t)row * 64 + lane] = h;
  float s = f * f;
#pragma unroll
  for (int o = 32; o; o >>= 1) s += __shfl_xor(s, o);
  if (lane == 0) {
    float A  = 0.5f * s;
    u16  hq  = f2bf(A);
    u16  lq  = f2bf(A - bf2f(hq));
    hlj[row] = (u32)hq | ((u32)lq << 16);
  }
}

// ---------------------------------------------------------------- screen: activity bits for one j, massively parallel
// grid (QT, SEGS), 4 waves/block; wave w covers k-tiles [seg*32 + w*8, +8)
__global__ __launch_bounds__(256) void screen_ker(const u16* __restrict__ xbj,
                                                  const u32* __restrict__ hlj,
                                                  u32* __restrict__ maskj)
{
  const int t = threadIdx.x;
  const int w = t >> 6, lane = t & 63, l31 = lane & 31, hi = lane >> 5;
  const int qtile = blockIdx.x;
  const int seg   = blockIdx.y;
  const int qrow  = qtile * 32 + l31;

  const u16* qp = xbj + (size_t)qrow * 64 + hi * 8;
  bf16x8 qf0 = *(const bf16x8*)(qp);
  bf16x8 qf1 = *(const bf16x8*)(qp + 16);
  bf16x8 qf2 = *(const bf16x8*)(qp + 32);
  bf16x8 qf3 = *(const bf16x8*)(qp + 48);
  u32 hlq = hlj[qrow];
  union { bf16x8 v; u32 d[4]; } qe, ke;
  qe.d[0] = hi ? 0u : hlq;
  qe.d[1] = hi ? 0u : 0x3F803F80u;
  qe.d[2] = 0u; qe.d[3] = 0u;
  ke.d[2] = 0u; ke.d[3] = 0u;
  const u32 ke0 = hi ? 0u : 0xBF80BF80u;

  f32x16 Z;
#pragma unroll
  for (int r = 0; r < 16; ++r) Z[r] = 0.f;

  u32 bits = 0;
  const int nt0 = seg * 32 + w * 8;
#pragma unroll
  for (int it = 0; it < 8; ++it) {
    const int nb = (nt0 + it) * 32;
    const u16* kp = xbj + (size_t)(nb + l31) * 64 + hi * 8;
    bf16x8 kf0 = *(const bf16x8*)(kp);
    bf16x8 kf1 = *(const bf16x8*)(kp + 16);
    bf16x8 kf2 = *(const bf16x8*)(kp + 32);
    bf16x8 kf3 = *(const bf16x8*)(kp + 48);
    u32 hlk = hlj[nb + l31];
    ke.d[0] = ke0;
    ke.d[1] = hi ? 0u : (hlk ^ 0x80008000u);
    f32x16 S = __builtin_amdgcn_mfma_f32_32x32x16_bf16(qf0, kf0, Z, 0, 0, 0);
    S = __builtin_amdgcn_mfma_f32_32x32x16_bf16(qf1, kf1, S, 0, 0, 0);
    S = __builtin_amdgcn_mfma_f32_32x32x16_bf16(qf2, kf2, S, 0, 0, 0);
    S = __builtin_amdgcn_mfma_f32_32x32x16_bf16(qf3, kf3, S, 0, 0, 0);
    S = __builtin_amdgcn_mfma_f32_32x32x16_bf16(qe.v, ke.v, S, 0, 0, 0);
    float m0 = fmaxf(S[0], S[1]),  m1 = fmaxf(S[2], S[3]);
    float m2 = fmaxf(S[4], S[5]),  m3 = fmaxf(S[6], S[7]);
    float m4 = fmaxf(S[8], S[9]),  m5 = fmaxf(S[10], S[11]);
    float m6 = fmaxf(S[12], S[13]), m7 = fmaxf(S[14], S[15]);
    float mx = fmaxf(fmaxf(fmaxf(m0, m1), fmaxf(m2, m3)),
                     fmaxf(fmaxf(m4, m5), fmaxf(m6, m7)));
    bits |= (__any(mx > -25.0f) ? 1u : 0u) << it;
  }
  if (lane == 0)
    ((unsigned char*)maskj)[((size_t)qtile * SEGS + seg) * 4 + w] = (unsigned char)bits;
}

// ---------------------------------------------------------------- fused: val_seg = (sum_j K_j) @ cs_i, active tiles only
template<int NJ>
__global__ __launch_bounds__(256) void fused_ker(const u16* __restrict__ xb,
                                                 const u32* __restrict__ hl,
                                                 const u16* __restrict__ csbT,
                                                 float* __restrict__ val,
                                                 const u32* __restrict__ mask)
{
  __shared__ __align__(16) u16 Pt[4][32 * 32];   // per-wave P transpose buffer

  const int t    = threadIdx.x;
  const int w    = t >> 6;
  const int lane = t & 63;
  const int l31  = lane & 31;
  const int hi   = lane >> 5;
  const int seg   = blockIdx.y;
  const int qtile = blockIdx.x * 4 + w;
  const int qrow  = qtile * 32 + l31;

  u32 m[NJ];
  u32 uni = 0;
#pragma unroll
  for (int j = 0; j < NJ; ++j) {
    m[j] = mask[((size_t)j * QT + qtile) * SEGS + seg];
    uni |= m[j];
  }
  if (!uni) return;

  float* vout = val + (size_t)seg * ((size_t)M_TOT * 64);

  bf16x8 qf[NJ][4];
  u32    hlq[NJ];
#pragma unroll
  for (int j = 0; j < NJ; ++j) {
    const u16* xbj = xb + (size_t)j * ((size_t)M_TOT * 64);
#pragma unroll
    for (int dk = 0; dk < 4; ++dk)
      qf[j][dk] = *(const bf16x8*)(xbj + (size_t)qrow * 64 + dk * 16 + hi * 8);
    hlq[j] = hl[j * M_TOT + qrow];
  }

  f32x16 acc0, acc1;
#pragma unroll
  for (int r = 0; r < 16; ++r) { acc0[r] = 0.f; acc1[r] = 0.f; }
  const int nb0 = seg * SEG;

  u32 rem = uni;
  while (rem) {
    const int nt = __ffs(rem) - 1;
    rem &= rem - 1;
    const int nb = nb0 + nt * 32;
    f32x16 P;
#pragma unroll
    for (int r = 0; r < 16; ++r) P[r] = 0.f;
#pragma unroll
    for (int j = 0; j < NJ; ++j) {
      if ((m[j] >> nt) & 1u) {
        const u16* xbj = xb + (size_t)j * ((size_t)M_TOT * 64);
        const u16* kp = xbj + (size_t)(nb + l31) * 64 + hi * 8;
        bf16x8 kf0 = *(const bf16x8*)(kp);
        bf16x8 kf1 = *(const bf16x8*)(kp + 16);
        bf16x8 kf2 = *(const bf16x8*)(kp + 32);
        bf16x8 kf3 = *(const bf16x8*)(kp + 48);
        u32 hlk = hl[j * M_TOT + nb + l31];
        f32x16 S;
#pragma unroll
        for (int r = 0; r < 16; ++r) S[r] = 0.f;
        S = __builtin_amdgcn_mfma_f32_32x32x16_bf16(qf[j][0], kf0, S, 0, 0, 0);
        S = __builtin_amdgcn_mfma_f32_32x32x16_bf16(qf[j][1], kf1, S, 0, 0, 0);
        S = __builtin_amdgcn_mfma_f32_32x32x16_bf16(qf[j][2], kf2, S, 0, 0, 0);
        S = __builtin_amdgcn_mfma_f32_32x32x16_bf16(qf[j][3], kf3, S, 0, 0, 0);
        union { bf16x8 v; u32 d[4]; } qe, ke;
        qe.d[0] = hi ? 0u : hlq[j];
        qe.d[1] = hi ? 0u : 0x3F803F80u;
        qe.d[2] = 0u; qe.d[3] = 0u;
        ke.d[0] = hi ? 0u : 0xBF80BF80u;
        ke.d[1] = hi ? 0u : (hlk ^ 0x80008000u);
        ke.d[2] = 0u; ke.d[3] = 0u;
        S = __builtin_amdgcn_mfma_f32_32x32x16_bf16(qe.v, ke.v, S, 0, 0, 0);
#pragma unroll
        for (int r = 0; r < 16; ++r) P[r] += __expf(S[r]);
      }
    }
    // P (D-layout) -> LDS (bf16) -> A-layout, per-wave region
    char* pw = (char*)&Pt[w][0];
#pragma unroll
    for (int r = 0; r < 16; ++r) {
      int qr = (r & 3) + 8 * (r >> 2) + 4 * hi;
      *(u16*)(pw + qr * 64 + ((l31 * 2) ^ ((qr & 3) << 4))) = f2bf(P[r]);
    }
    asm volatile("s_waitcnt lgkmcnt(0)" ::: "memory");
    bf16x8 pa0 = *(const bf16x8*)(pw + l31 * 64 + ((0  + hi * 16) ^ ((l31 & 3) << 4)));
    bf16x8 pa1 = *(const bf16x8*)(pw + l31 * 64 + ((32 + hi * 16) ^ ((l31 & 3) << 4)));
    asm volatile("s_waitcnt lgkmcnt(0)" ::: "memory");   // drain before next nt's writes (WAR)
    bf16x8 v00 = *(const bf16x8*)(csbT + (size_t)l31 * N_S + nb + hi * 8);
    bf16x8 v01 = *(const bf16x8*)(csbT + (size_t)l31 * N_S + nb + 16 + hi * 8);
    bf16x8 v10 = *(const bf16x8*)(csbT + (size_t)(32 + l31) * N_S + nb + hi * 8);
    bf16x8 v11 = *(const bf16x8*)(csbT + (size_t)(32 + l31) * N_S + nb + 16 + hi * 8);
    acc0 = __builtin_amdgcn_mfma_f32_32x32x16_bf16(pa0, v00, acc0, 0, 0, 0);
    acc0 = __builtin_amdgcn_mfma_f32_32x32x16_bf16(pa1, v01, acc0, 0, 0, 0);
    acc1 = __builtin_amdgcn_mfma_f32_32x32x16_bf16(pa0, v10, acc1, 0, 0, 0);
    acc1 = __builtin_amdgcn_mfma_f32_32x32x16_bf16(pa1, v11, acc1, 0, 0, 0);
  }

#pragma unroll
  for (int r = 0; r < 16; ++r) {
    int qr = (r & 3) + 8 * (r >> 2) + 4 * hi;
    size_t row = (size_t)(qtile * 32 + qr);
    vout[row * 64 + l31]      = acc0[r];
    vout[row * 64 + 32 + l31] = acc1[r];
  }
}

// ---------------------------------------------------------------- apply: x[:,i+1] += val; emit xb/hl for j=i+1; dot partials
__global__ __launch_bounds__(256) void apply_ker(const float* __restrict__ val,
                                                 const float* __restrict__ css,
                                                 float* __restrict__ x, int i, int nj,
                                                 const u32* __restrict__ mask,
                                                 float* __restrict__ dotpart,
                                                 u16* __restrict__ xbn,
                                                 u32* __restrict__ hln)
{
  __shared__ float red[256];
  const int t = threadIdx.x;
  const int qtile = blockIdx.x;
  const int row = qtile * 32 + (t >> 3);
  const int coff = (t & 7) * 8;
  bool f[SEGS];
  bool anyf = false;
#pragma unroll
  for (int s = 0; s < SEGS; ++s) {
    u32 u = 0;
    for (int j = 0; j < nj; ++j) u |= mask[((size_t)j * QT + qtile) * SEGS + s];
    f[s] = (u != 0);
    anyf = anyf || f[s];
  }
  float v[8];
#pragma unroll
  for (int e = 0; e < 8; ++e) v[e] = 0.f;
  float dp = 0.f;
  float* xp = x + (size_t)row * 256 + (size_t)(i + 1) * 64 + coff;
  float4 xa = *(const float4*)xp;
  float4 xb4 = *(const float4*)(xp + 4);
  if (anyf) {
#pragma unroll
    for (int s = 0; s < SEGS; ++s) if (f[s]) {
      const float* vp = val + (size_t)s * ((size_t)M_TOT * 64) + (size_t)row * 64 + coff;
      float4 a = *(const float4*)vp;
      float4 b = *(const float4*)(vp + 4);
      v[0] += a.x; v[1] += a.y; v[2] += a.z; v[3] += a.w;
      v[4] += b.x; v[5] += b.y; v[6] += b.z; v[7] += b.w;
    }
    xa.x += v[0]; xa.y += v[1]; xa.z += v[2]; xa.w += v[3];
    xb4.x += v[4]; xb4.y += v[5]; xb4.z += v[6]; xb4.w += v[7];
    *(float4*)xp = xa;
    *(float4*)(xp + 4) = xb4;
    if (row < N_S) {
      const float* cp = css + (size_t)row * 192 + (size_t)i * 64 + coff;
      float4 ca = *(const float4*)cp;
      float4 cb = *(const float4*)(cp + 4);
      dp = ca.x * v[0] + ca.y * v[1] + ca.z * v[2] + ca.w * v[3]
         + cb.x * v[4] + cb.y * v[5] + cb.z * v[6] + cb.w * v[7];
    }
  }
  if (xbn) {
    float xv[8] = {xa.x, xa.y, xa.z, xa.w, xb4.x, xb4.y, xb4.z, xb4.w};
    u16 h[8];
    float s2 = 0.f;
#pragma unroll
    for (int e = 0; e < 8; ++e) {
      h[e] = f2bf(xv[e]);
      float fb = bf2f(h[e]);
      s2 += fb * fb;
    }
    *(int4*)(xbn + (size_t)row * 64 + coff) = *(int4*)h;
    s2 += __shfl_xor(s2, 1);
    s2 += __shfl_xor(s2, 2);
    s2 += __shfl_xor(s2, 4);
    if ((t & 7) == 0) {
      float A = 0.5f * s2;
      u16 hq = f2bf(A);
      u16 lq = f2bf(A - bf2f(hq));
      hln[row] = (u32)hq | ((u32)lq << 16);
    }
  }
  red[t] = dp; __syncthreads();
#pragma unroll
  for (int o = 128; o; o >>= 1) {
    if (t < o) red[t] += red[t + o];
    __syncthreads();
  }
  if (t == 0) dotpart[i * QT + qtile] = red[0];
}

// ---------------------------------------------------------------- final: outcopy + fixed-order reg reduce
__global__ __launch_bounds__(256) void final_ker(const float* __restrict__ x,
                                                 const float* __restrict__ regpart,
                                                 const float* __restrict__ dotpart,
                                                 float* __restrict__ out)
{
  if (blockIdx.x < 512) {
    int idx = blockIdx.x * 256 + threadIdx.x;   // < 131072
    int r = idx >> 6, c = idx & 63;
    out[idx] = x[(size_t)(N_S + r) * 256 + 192 + c];
    return;
  }
  __shared__ float red[256];
  float s = 0.f;
  for (int idx = threadIdx.x; idx < 3 * QT; idx += 256) s += dotpart[idx];
  if (threadIdx.x < 64) s += regpart[threadIdx.x];
  red[threadIdx.x] = s; __syncthreads();
#pragma unroll
  for (int o = 128; o; o >>= 1) {
    if (threadIdx.x < o) red[threadIdx.x] += red[threadIdx.x + o];
    __syncthreads();
  }
  if (threadIdx.x == 0) out[131072] = red[0];
}

// ================================================================ launch
extern "C" void kernel_launch(void* const* d_in, const int* in_sizes, int n_in,
                              void* d_out, int out_size, void* d_ws, size_t ws_size,
                              hipStream_t stream)
{
  const float* data = (const float*)d_in[0];
  const float* inp  = (const float*)d_in[1];
  const float* W    = (const float*)d_in[2];
  const float* bias = (const float*)d_in[3];
  const float* css  = (const float*)d_in[4];
  float* out = (float*)d_out;

  char* ws = (char*)d_ws;
  const size_t OFF_X    = 0;                         // 10,485,760
  const size_t OFF_XB   = 10485760;                  //  3,932,160
  const size_t OFF_HL   = OFF_XB + 3932160;          //    122,880
  const size_t OFF_CSBT = OFF_HL + 122880;           //  3,145,728
  const size_t OFF_VAL  = OFF_CSBT + 3145728;        // 20,971,520
  const size_t OFF_MASK = OFF_VAL + 20971520;        //     30,720
  const size_t OFF_REGW = OFF_MASK + 30720;          //        256
  const size_t OFF_DOT  = OFF_REGW + 256;            //      3,840

  float* x      = (float*)(ws + OFF_X);
  u16*   xb     = (u16*)  (ws + OFF_XB);
  u32*   hl     = (u32*)  (ws + OFF_HL);
  u16*   csbT   = (u16*)  (ws + OFF_CSBT);
  float* val    = (float*)(ws + OFF_VAL);
  u32*   mask   = (u32*)  (ws + OFF_MASK);
  float* regpart= (float*)(ws + OFF_REGW);
  float* dotpart= (float*)(ws + OFF_DOT);

  const size_t XB_STRIDE = (size_t)M_TOT * 64;     // u16 elems
  const size_t CS_STRIDE = (size_t)64 * N_S;       // u16 elems
  const size_t MK_STRIDE = (size_t)QT * SEGS;      // u32 elems

  gemm_x   <<<dim3(160, 4), 256, 0, stream>>>(data, inp, W, bias, x);
  prep_csT <<<dim3(128, 3), 256, 0, stream>>>(css, csbT);
  regw_ker <<<64, 256, 0, stream>>>(W, bias, regpart);
  prep_xb  <<<2560, 256, 0, stream>>>(x, 0, xb, hl);
  screen_ker<<<dim3(QT, SEGS), 256, 0, stream>>>(xb, hl, mask);

  // i = 0  (apply also emits xb/hl for j=1)
  fused_ker<1><<<dim3(80, SEGS), 256, 0, stream>>>(xb, hl, csbT, val, mask);
  apply_ker<<<QT, 256, 0, stream>>>(val, css, x, 0, 1, mask, dotpart,
                                    xb + XB_STRIDE, hl + M_TOT);
  screen_ker<<<dim3(QT, SEGS), 256, 0, stream>>>(xb + XB_STRIDE, hl + M_TOT, mask + MK_STRIDE);

  // i = 1  (apply also emits xb/hl for j=2)
  fused_ker<2><<<dim3(80, SEGS), 256, 0, stream>>>(xb, hl, csbT + CS_STRIDE, val, mask);
  apply_ker<<<QT, 256, 0, stream>>>(val, css, x, 1, 2, mask, dotpart,
                                    xb + 2 * XB_STRIDE, hl + 2 * M_TOT);
  screen_ker<<<dim3(QT, SEGS), 256, 0, stream>>>(xb + 2 * XB_STRIDE, hl + 2 * M_TOT, mask + 2 * MK_STRIDE);

  // i = 2
  fused_ker<3><<<dim3(80, SEGS), 256, 0, stream>>>(xb, hl, csbT + 2 * CS_STRIDE, val, mask);
  apply_ker<<<QT, 256, 0, stream>>>(val, css, x, 2, 3, mask, dotpart,
                                    (u16*)nullptr, (u32*)nullptr);

  final_ker<<<513, 256, 0, stream>>>(x, regpart, dotpart, out);
}

// Round 6
// 148.177 us; speedup vs baseline: 1.7051x; 1.4548x over previous
//
#include <hip/hip_runtime.h>
#include <hip/hip_bf16.h>

typedef unsigned short u16;
typedef unsigned int   u32;
typedef __attribute__((ext_vector_type(8)))  short bf16x8;
typedef __attribute__((ext_vector_type(16))) float f32x16;

#define N_S   8192
#define M_TOT 10240
#define SEGS  8
#define SEG   1024
#define QT    320     // 32-row q-tiles over M_TOT

__device__ __forceinline__ u16 f2bf(float f) {
  u32 x = __float_as_uint(f);
  u32 r = x + 0x7FFFu + ((x >> 16) & 1u);
  return (u16)(r >> 16);
}
__device__ __forceinline__ float bf2f(u16 h) {
  return __uint_as_float(((u32)h) << 16);
}

// ---------------------------------------------------------------- x = A @ W^T + b  (bf16 MFMA, fp32 accum)
__global__ __launch_bounds__(256) void gemm_x(const float* __restrict__ data,
                                              const float* __restrict__ inp,
                                              const float* __restrict__ W,
                                              const float* __restrict__ bias,
                                              float* __restrict__ x)
{
  __shared__ __align__(16) u16 At[64 * 256];   // 32KB, XOR-swizzled
  __shared__ __align__(16) u16 Wt[64 * 256];   // 32KB, XOR-swizzled
  const int t  = threadIdx.x;
  const int rb = blockIdx.x * 64, cb = blockIdx.y * 64;

#pragma unroll
  for (int it = 0; it < 8; ++it) {
    int c = it * 256 + t;                    // chunk of 8 bf16
    int row = c >> 5, c8 = c & 31;
    int grow = rb + row;
    const float* src = (grow < N_S) ? data + (size_t)grow * 256 + c8 * 8
                                    : inp + (size_t)(grow - N_S) * 256 + c8 * 8;
    float4 v0 = *(const float4*)src;
    float4 v1 = *(const float4*)(src + 4);
    u16 h[8] = {f2bf(v0.x), f2bf(v0.y), f2bf(v0.z), f2bf(v0.w),
                f2bf(v1.x), f2bf(v1.y), f2bf(v1.z), f2bf(v1.w)};
    *(int4*)((char*)At + row * 512 + ((c8 * 16) ^ ((row & 7) << 4))) = *(int4*)h;

    const float* wsrc = W + (size_t)(cb + row) * 256 + c8 * 8;
    float4 w0 = *(const float4*)wsrc;
    float4 w1 = *(const float4*)(wsrc + 4);
    u16 g[8] = {f2bf(w0.x), f2bf(w0.y), f2bf(w0.z), f2bf(w0.w),
                f2bf(w1.x), f2bf(w1.y), f2bf(w1.z), f2bf(w1.w)};
    *(int4*)((char*)Wt + row * 512 + ((c8 * 16) ^ ((row & 7) << 4))) = *(int4*)g;
  }
  __syncthreads();

  const int w = t >> 6, lane = t & 63, l31 = lane & 31, hi = lane >> 5;
  const int wr = (w >> 1) * 32, wc = (w & 1) * 32;
  f32x16 acc;
#pragma unroll
  for (int r = 0; r < 16; ++r) acc[r] = 0.f;
  const char* Ab = (const char*)At + (size_t)(wr + l31) * 512;
  const char* Bb = (const char*)Wt + (size_t)(wc + l31) * 512;
  const int rx = (l31 & 7) << 4;
#pragma unroll
  for (int k0 = 0; k0 < 256; k0 += 16) {
    bf16x8 af = *(const bf16x8*)(Ab + ((k0 * 2 + hi * 16) ^ rx));
    bf16x8 bfv = *(const bf16x8*)(Bb + ((k0 * 2 + hi * 16) ^ rx));
    acc = __builtin_amdgcn_mfma_f32_32x32x16_bf16(af, bfv, acc, 0, 0, 0);
  }
  float bv = bias[cb + wc + l31];
#pragma unroll
  for (int r = 0; r < 16; ++r) {
    int qr = (r & 3) + 8 * (r >> 2) + 4 * hi;
    x[(size_t)(rb + wr + qr) * 256 + cb + wc + l31] = acc[r] + bv;
  }
}

// ---------------------------------------------------------------- csbT[i][c][r] = bf16(c_ss[r][i*64+c])
__global__ __launch_bounds__(256) void prep_csT(const float* __restrict__ css,
                                                u16* __restrict__ csbT)
{
  __shared__ float tile[64][65];
  const int i  = blockIdx.y;
  const int r0 = blockIdx.x * 64;
  const int t  = threadIdx.x;
#pragma unroll
  for (int it = 0; it < 4; ++it) {
    int r  = (t >> 4) + it * 16;
    int c4 = (t & 15) * 4;
    float4 v = *(const float4*)(css + (size_t)(r0 + r) * 192 + i * 64 + c4);
    tile[r][c4] = v.x; tile[r][c4 + 1] = v.y; tile[r][c4 + 2] = v.z; tile[r][c4 + 3] = v.w;
  }
  __syncthreads();
  const int c = t >> 2, rq = (t & 3) * 16;
  u16 tmp[16];
#pragma unroll
  for (int e = 0; e < 16; ++e) tmp[e] = f2bf(tile[rq + e][c]);
  u16* dst = csbT + (size_t)i * (64 * (size_t)N_S) + (size_t)c * N_S + r0 + rq;
  *(int4*)dst       = *(int4*)tmp;
  *(int4*)(dst + 8) = *(int4*)(tmp + 8);
}

// ---------------------------------------------------------------- reg_w partials: 64 blocks, fixed-order
__global__ __launch_bounds__(256) void regw_ker(const float* __restrict__ W,
                                                const float* __restrict__ bias,
                                                float* __restrict__ regpart)
{
  __shared__ float red[256];
  const int t = threadIdx.x, b = blockIdx.x;
  float4 v = *(const float4*)(W + (size_t)b * 1024 + t * 4);
  float s = v.x * v.x + v.y * v.y + v.z * v.z + v.w * v.w;
  if (b == 0) { float bv = bias[t]; s += bv * bv; }
  red[t] = s; __syncthreads();
#pragma unroll
  for (int o = 128; o; o >>= 1) {
    if (t < o) red[t] += red[t + o];
    __syncthreads();
  }
  if (t == 0) regpart[b] = red[0];
}

// ---------------------------------------------------------------- bf16 chunk + Dekker-split 0.5*|row|^2 (from bf16 values)
__global__ __launch_bounds__(256) void prep_xb(const float* __restrict__ x, int j,
                                               u16* __restrict__ xbj, u32* __restrict__ hlj)
{
  const int w = threadIdx.x >> 6, lane = threadIdx.x & 63;
  const int row = blockIdx.x * 4 + w;
  float v = x[(size_t)row * 256 + (size_t)j * 64 + lane];
  u16 h = f2bf(v);
  float f = bf2f(h);
  xbj[(size_t)row * 64 + lane] = h;
  float s = f * f;
#pragma unroll
  for (int o = 32; o; o >>= 1) s += __shfl_xor(s, o);
  if (lane == 0) {
    float A  = 0.5f * s;
    u16  hq  = f2bf(A);
    u16  lq  = f2bf(A - bf2f(hq));
    hlj[row] = (u32)hq | ((u32)lq << 16);
  }
}

// ---------------------------------------------------------------- screen: activity bits, 4 qtiles per wave share K loads
// grid (80, SEGS, 4), 64 threads; wave covers qtiles qq*4..+3, k-tiles [seg*32 + z*8, +8)
__global__ __launch_bounds__(64) void screen_ker(const u16* __restrict__ xbj,
                                                 const u32* __restrict__ hlj,
                                                 u32* __restrict__ maskj)
{
  const int lane = threadIdx.x & 63, l31 = lane & 31, hi = lane >> 5;
  const int qq  = blockIdx.x;
  const int seg = blockIdx.y;
  const int w   = blockIdx.z;

  bf16x8 qf[4][4];
  u32 hlq[4];
#pragma unroll
  for (int q = 0; q < 4; ++q) {
    const int qrow = (qq * 4 + q) * 32 + l31;
    const u16* qp = xbj + (size_t)qrow * 64 + hi * 8;
#pragma unroll
    for (int d = 0; d < 4; ++d) qf[q][d] = *(const bf16x8*)(qp + d * 16);
    hlq[q] = hlj[qrow];
  }

  f32x16 Z;
#pragma unroll
  for (int r = 0; r < 16; ++r) Z[r] = 0.f;

  u32 bits0 = 0, bits1 = 0, bits2 = 0, bits3 = 0;
  const int nt0 = seg * 32 + w * 8;
#pragma unroll
  for (int it = 0; it < 8; ++it) {
    const int nb = (nt0 + it) * 32;
    const u16* kp = xbj + (size_t)(nb + l31) * 64 + hi * 8;
    bf16x8 kf0 = *(const bf16x8*)(kp);
    bf16x8 kf1 = *(const bf16x8*)(kp + 16);
    bf16x8 kf2 = *(const bf16x8*)(kp + 32);
    bf16x8 kf3 = *(const bf16x8*)(kp + 48);
    u32 hlk = hlj[nb + l31];
    union { bf16x8 v; u32 d[4]; } ke;
    ke.d[0] = hi ? 0u : 0xBF80BF80u;
    ke.d[1] = hi ? 0u : (hlk ^ 0x80008000u);
    ke.d[2] = 0u; ke.d[3] = 0u;
#pragma unroll
    for (int q = 0; q < 4; ++q) {
      f32x16 S = __builtin_amdgcn_mfma_f32_32x32x16_bf16(qf[q][0], kf0, Z, 0, 0, 0);
      S = __builtin_amdgcn_mfma_f32_32x32x16_bf16(qf[q][1], kf1, S, 0, 0, 0);
      S = __builtin_amdgcn_mfma_f32_32x32x16_bf16(qf[q][2], kf2, S, 0, 0, 0);
      S = __builtin_amdgcn_mfma_f32_32x32x16_bf16(qf[q][3], kf3, S, 0, 0, 0);
      union { bf16x8 v; u32 d[4]; } qe;
      qe.d[0] = hi ? 0u : hlq[q];
      qe.d[1] = hi ? 0u : 0x3F803F80u;
      qe.d[2] = 0u; qe.d[3] = 0u;
      S = __builtin_amdgcn_mfma_f32_32x32x16_bf16(qe.v, ke.v, S, 0, 0, 0);
      float m0 = fmaxf(S[0], S[1]),  m1 = fmaxf(S[2], S[3]);
      float m2 = fmaxf(S[4], S[5]),  m3 = fmaxf(S[6], S[7]);
      float m4 = fmaxf(S[8], S[9]),  m5 = fmaxf(S[10], S[11]);
      float m6 = fmaxf(S[12], S[13]), m7 = fmaxf(S[14], S[15]);
      float mx = fmaxf(fmaxf(fmaxf(m0, m1), fmaxf(m2, m3)),
                       fmaxf(fmaxf(m4, m5), fmaxf(m6, m7)));
      u32 b = (__any(mx > -25.0f) ? 1u : 0u) << it;
      if (q == 0) bits0 |= b;
      else if (q == 1) bits1 |= b;
      else if (q == 2) bits2 |= b;
      else bits3 |= b;
    }
  }
  if (lane == 0) {
    unsigned char* mb = (unsigned char*)maskj;
    mb[((size_t)(qq * 4 + 0) * SEGS + seg) * 4 + w] = (unsigned char)bits0;
    mb[((size_t)(qq * 4 + 1) * SEGS + seg) * 4 + w] = (unsigned char)bits1;
    mb[((size_t)(qq * 4 + 2) * SEGS + seg) * 4 + w] = (unsigned char)bits2;
    mb[((size_t)(qq * 4 + 3) * SEGS + seg) * 4 + w] = (unsigned char)bits3;
  }
}

// ---------------------------------------------------------------- fused: val_seg = (sum_j K_j) @ cs_i, active tiles only
template<int NJ>
__global__ __launch_bounds__(256) void fused_ker(const u16* __restrict__ xb,
                                                 const u32* __restrict__ hl,
                                                 const u16* __restrict__ csbT,
                                                 float* __restrict__ val,
                                                 const u32* __restrict__ mask)
{
  __shared__ __align__(16) u16 Pt[4][32 * 32];   // per-wave P transpose buffer

  const int t    = threadIdx.x;
  const int w    = t >> 6;
  const int lane = t & 63;
  const int l31  = lane & 31;
  const int hi   = lane >> 5;
  const int seg   = blockIdx.y;
  const int qtile = blockIdx.x * 4 + w;
  const int qrow  = qtile * 32 + l31;

  u32 m[NJ];
  u32 uni = 0;
#pragma unroll
  for (int j = 0; j < NJ; ++j) {
    m[j] = mask[((size_t)j * QT + qtile) * SEGS + seg];
    uni |= m[j];
  }
  if (!uni) return;

  float* vout = val + (size_t)seg * ((size_t)M_TOT * 64);

  bf16x8 qf[NJ][4];
  u32    hlq[NJ];
#pragma unroll
  for (int j = 0; j < NJ; ++j) {
    const u16* xbj = xb + (size_t)j * ((size_t)M_TOT * 64);
#pragma unroll
    for (int dk = 0; dk < 4; ++dk)
      qf[j][dk] = *(const bf16x8*)(xbj + (size_t)qrow * 64 + dk * 16 + hi * 8);
    hlq[j] = hl[j * M_TOT + qrow];
  }

  f32x16 acc0, acc1;
#pragma unroll
  for (int r = 0; r < 16; ++r) { acc0[r] = 0.f; acc1[r] = 0.f; }
  const int nb0 = seg * SEG;

  u32 rem = uni;
  while (rem) {
    const int nt = __ffs(rem) - 1;
    rem &= rem - 1;
    const int nb = nb0 + nt * 32;
    f32x16 P;
#pragma unroll
    for (int r = 0; r < 16; ++r) P[r] = 0.f;
#pragma unroll
    for (int j = 0; j < NJ; ++j) {
      if ((m[j] >> nt) & 1u) {
        const u16* xbj = xb + (size_t)j * ((size_t)M_TOT * 64);
        const u16* kp = xbj + (size_t)(nb + l31) * 64 + hi * 8;
        bf16x8 kf0 = *(const bf16x8*)(kp);
        bf16x8 kf1 = *(const bf16x8*)(kp + 16);
        bf16x8 kf2 = *(const bf16x8*)(kp + 32);
        bf16x8 kf3 = *(const bf16x8*)(kp + 48);
        u32 hlk = hl[j * M_TOT + nb + l31];
        f32x16 S;
#pragma unroll
        for (int r = 0; r < 16; ++r) S[r] = 0.f;
        S = __builtin_amdgcn_mfma_f32_32x32x16_bf16(qf[j][0], kf0, S, 0, 0, 0);
        S = __builtin_amdgcn_mfma_f32_32x32x16_bf16(qf[j][1], kf1, S, 0, 0, 0);
        S = __builtin_amdgcn_mfma_f32_32x32x16_bf16(qf[j][2], kf2, S, 0, 0, 0);
        S = __builtin_amdgcn_mfma_f32_32x32x16_bf16(qf[j][3], kf3, S, 0, 0, 0);
        union { bf16x8 v; u32 d[4]; } qe, ke;
        qe.d[0] = hi ? 0u : hlq[j];
        qe.d[1] = hi ? 0u : 0x3F803F80u;
        qe.d[2] = 0u; qe.d[3] = 0u;
        ke.d[0] = hi ? 0u : 0xBF80BF80u;
        ke.d[1] = hi ? 0u : (hlk ^ 0x80008000u);
        ke.d[2] = 0u; ke.d[3] = 0u;
        S = __builtin_amdgcn_mfma_f32_32x32x16_bf16(qe.v, ke.v, S, 0, 0, 0);
#pragma unroll
        for (int r = 0; r < 16; ++r) P[r] += __expf(S[r]);
      }
    }
    // P (D-layout) -> LDS (bf16) -> A-layout, per-wave region
    char* pw = (char*)&Pt[w][0];
#pragma unroll
    for (int r = 0; r < 16; ++r) {
      int qr = (r & 3) + 8 * (r >> 2) + 4 * hi;
      *(u16*)(pw + qr * 64 + ((l31 * 2) ^ ((qr & 3) << 4))) = f2bf(P[r]);
    }
    asm volatile("s_waitcnt lgkmcnt(0)" ::: "memory");
    bf16x8 pa0 = *(const bf16x8*)(pw + l31 * 64 + ((0  + hi * 16) ^ ((l31 & 3) << 4)));
    bf16x8 pa1 = *(const bf16x8*)(pw + l31 * 64 + ((32 + hi * 16) ^ ((l31 & 3) << 4)));
    asm volatile("s_waitcnt lgkmcnt(0)" ::: "memory");   // drain before next nt's writes (WAR)
    bf16x8 v00 = *(const bf16x8*)(csbT + (size_t)l31 * N_S + nb + hi * 8);
    bf16x8 v01 = *(const bf16x8*)(csbT + (size_t)l31 * N_S + nb + 16 + hi * 8);
    bf16x8 v10 = *(const bf16x8*)(csbT + (size_t)(32 + l31) * N_S + nb + hi * 8);
    bf16x8 v11 = *(const bf16x8*)(csbT + (size_t)(32 + l31) * N_S + nb + 16 + hi * 8);
    acc0 = __builtin_amdgcn_mfma_f32_32x32x16_bf16(pa0, v00, acc0, 0, 0, 0);
    acc0 = __builtin_amdgcn_mfma_f32_32x32x16_bf16(pa1, v01, acc0, 0, 0, 0);
    acc1 = __builtin_amdgcn_mfma_f32_32x32x16_bf16(pa0, v10, acc1, 0, 0, 0);
    acc1 = __builtin_amdgcn_mfma_f32_32x32x16_bf16(pa1, v11, acc1, 0, 0, 0);
  }

#pragma unroll
  for (int r = 0; r < 16; ++r) {
    int qr = (r & 3) + 8 * (r >> 2) + 4 * hi;
    size_t row = (size_t)(qtile * 32 + qr);
    vout[row * 64 + l31]      = acc0[r];
    vout[row * 64 + 32 + l31] = acc1[r];
  }
}

// ---------------------------------------------------------------- apply: x[:,i+1] += val; emit xb/hl for j=i+1; dot partials
__global__ __launch_bounds__(256) void apply_ker(const float* __restrict__ val,
                                                 const float* __restrict__ css,
                                                 float* __restrict__ x, int i, int nj,
                                                 const u32* __restrict__ mask,
                                                 float* __restrict__ dotpart,
                                                 u16* __restrict__ xbn,
                                                 u32* __restrict__ hln)
{
  __shared__ float red[256];
  const int t = threadIdx.x;
  const int qtile = blockIdx.x;
  const int row = qtile * 32 + (t >> 3);
  const int coff = (t & 7) * 8;
  bool f[SEGS];
  bool anyf = false;
#pragma unroll
  for (int s = 0; s < SEGS; ++s) {
    u32 u = 0;
    for (int j = 0; j < nj; ++j) u |= mask[((size_t)j * QT + qtile) * SEGS + s];
    f[s] = (u != 0);
    anyf = anyf || f[s];
  }
  float v[8];
#pragma unroll
  for (int e = 0; e < 8; ++e) v[e] = 0.f;
  float dp = 0.f;
  float* xp = x + (size_t)row * 256 + (size_t)(i + 1) * 64 + coff;
  float4 xa = *(const float4*)xp;
  float4 xb4 = *(const float4*)(xp + 4);
  if (anyf) {
#pragma unroll
    for (int s = 0; s < SEGS; ++s) if (f[s]) {
      const float* vp = val + (size_t)s * ((size_t)M_TOT * 64) + (size_t)row * 64 + coff;
      float4 a = *(const float4*)vp;
      float4 b = *(const float4*)(vp + 4);
      v[0] += a.x; v[1] += a.y; v[2] += a.z; v[3] += a.w;
      v[4] += b.x; v[5] += b.y; v[6] += b.z; v[7] += b.w;
    }
    xa.x += v[0]; xa.y += v[1]; xa.z += v[2]; xa.w += v[3];
    xb4.x += v[4]; xb4.y += v[5]; xb4.z += v[6]; xb4.w += v[7];
    *(float4*)xp = xa;
    *(float4*)(xp + 4) = xb4;
    if (row < N_S) {
      const float* cp = css + (size_t)row * 192 + (size_t)i * 64 + coff;
      float4 ca = *(const float4*)cp;
      float4 cb = *(const float4*)(cp + 4);
      dp = ca.x * v[0] + ca.y * v[1] + ca.z * v[2] + ca.w * v[3]
         + cb.x * v[4] + cb.y * v[5] + cb.z * v[6] + cb.w * v[7];
    }
  }
  if (xbn) {
    float xv[8] = {xa.x, xa.y, xa.z, xa.w, xb4.x, xb4.y, xb4.z, xb4.w};
    u16 h[8];
    float s2 = 0.f;
#pragma unroll
    for (int e = 0; e < 8; ++e) {
      h[e] = f2bf(xv[e]);
      float fb = bf2f(h[e]);
      s2 += fb * fb;
    }
    *(int4*)(xbn + (size_t)row * 64 + coff) = *(int4*)h;
    s2 += __shfl_xor(s2, 1);
    s2 += __shfl_xor(s2, 2);
    s2 += __shfl_xor(s2, 4);
    if ((t & 7) == 0) {
      float A = 0.5f * s2;
      u16 hq = f2bf(A);
      u16 lq = f2bf(A - bf2f(hq));
      hln[row] = (u32)hq | ((u32)lq << 16);
    }
  }
  red[t] = dp; __syncthreads();
#pragma unroll
  for (int o = 128; o; o >>= 1) {
    if (t < o) red[t] += red[t + o];
    __syncthreads();
  }
  if (t == 0) dotpart[i * QT + qtile] = red[0];
}

// ---------------------------------------------------------------- final: outcopy + fixed-order reg reduce
__global__ __launch_bounds__(256) void final_ker(const float* __restrict__ x,
                                                 const float* __restrict__ regpart,
                                                 const float* __restrict__ dotpart,
                                                 float* __restrict__ out)
{
  if (blockIdx.x < 512) {
    int idx = blockIdx.x * 256 + threadIdx.x;   // < 131072
    int r = idx >> 6, c = idx & 63;
    out[idx] = x[(size_t)(N_S + r) * 256 + 192 + c];
    return;
  }
  __shared__ float red[256];
  float s = 0.f;
  for (int idx = threadIdx.x; idx < 3 * QT; idx += 256) s += dotpart[idx];
  if (threadIdx.x < 64) s += regpart[threadIdx.x];
  red[threadIdx.x] = s; __syncthreads();
#pragma unroll
  for (int o = 128; o; o >>= 1) {
    if (threadIdx.x < o) red[threadIdx.x] += red[threadIdx.x + o];
    __syncthreads();
  }
  if (threadIdx.x == 0) out[131072] = red[0];
}

// ================================================================ launch
extern "C" void kernel_launch(void* const* d_in, const int* in_sizes, int n_in,
                              void* d_out, int out_size, void* d_ws, size_t ws_size,
                              hipStream_t stream)
{
  const float* data = (const float*)d_in[0];
  const float* inp  = (const float*)d_in[1];
  const float* W    = (const float*)d_in[2];
  const float* bias = (const float*)d_in[3];
  const float* css  = (const float*)d_in[4];
  float* out = (float*)d_out;

  char* ws = (char*)d_ws;
  const size_t OFF_X    = 0;                         // 10,485,760
  const size_t OFF_XB   = 10485760;                  //  3,932,160
  const size_t OFF_HL   = OFF_XB + 3932160;          //    122,880
  const size_t OFF_CSBT = OFF_HL + 122880;           //  3,145,728
  const size_t OFF_VAL  = OFF_CSBT + 3145728;        // 20,971,520
  const size_t OFF_MASK = OFF_VAL + 20971520;        //     30,720
  const size_t OFF_REGW = OFF_MASK + 30720;          //        256
  const size_t OFF_DOT  = OFF_REGW + 256;            //      3,840

  float* x      = (float*)(ws + OFF_X);
  u16*   xb     = (u16*)  (ws + OFF_XB);
  u32*   hl     = (u32*)  (ws + OFF_HL);
  u16*   csbT   = (u16*)  (ws + OFF_CSBT);
  float* val    = (float*)(ws + OFF_VAL);
  u32*   mask   = (u32*)  (ws + OFF_MASK);
  float* regpart= (float*)(ws + OFF_REGW);
  float* dotpart= (float*)(ws + OFF_DOT);

  const size_t XB_STRIDE = (size_t)M_TOT * 64;     // u16 elems
  const size_t CS_STRIDE = (size_t)64 * N_S;       // u16 elems
  const size_t MK_STRIDE = (size_t)QT * SEGS;      // u32 elems

  gemm_x   <<<dim3(160, 4), 256, 0, stream>>>(data, inp, W, bias, x);
  prep_csT <<<dim3(128, 3), 256, 0, stream>>>(css, csbT);
  regw_ker <<<64, 256, 0, stream>>>(W, bias, regpart);
  prep_xb  <<<2560, 256, 0, stream>>>(x, 0, xb, hl);
  screen_ker<<<dim3(80, SEGS, 4), 64, 0, stream>>>(xb, hl, mask);

  // i = 0  (apply also emits xb/hl for j=1)
  fused_ker<1><<<dim3(80, SEGS), 256, 0, stream>>>(xb, hl, csbT, val, mask);
  apply_ker<<<QT, 256, 0, stream>>>(val, css, x, 0, 1, mask, dotpart,
                                    xb + XB_STRIDE, hl + M_TOT);
  screen_ker<<<dim3(80, SEGS, 4), 64, 0, stream>>>(xb + XB_STRIDE, hl + M_TOT, mask + MK_STRIDE);

  // i = 1  (apply also emits xb/hl for j=2)
  fused_ker<2><<<dim3(80, SEGS), 256, 0, stream>>>(xb, hl, csbT + CS_STRIDE, val, mask);
  apply_ker<<<QT, 256, 0, stream>>>(val, css, x, 1, 2, mask, dotpart,
                                    xb + 2 * XB_STRIDE, hl + 2 * M_TOT);
  screen_ker<<<dim3(80, SEGS, 4), 64, 0, stream>>>(xb + 2 * XB_STRIDE, hl + 2 * M_TOT, mask + 2 * MK_STRIDE);

  // i = 2
  fused_ker<3><<<dim3(80, SEGS), 256, 0, stream>>>(xb, hl, csbT + 2 * CS_STRIDE, val, mask);
  apply_ker<<<QT, 256, 0, stream>>>(val, css, x, 2, 3, mask, dotpart,
                                    (u16*)nullptr, (u32*)nullptr);

  final_ker<<<513, 256, 0, stream>>>(x, regpart, dotpart, out);
}